// Round 10
// baseline (61.577 us; speedup 1.0000x reference)
//
#include <hip/hip_runtime.h>

// SSIM loss v9: MFMA-based. Per 16x16 output tile and channel:
//   T(32x16)  = X(32x32) . Wh(32x16)     (2 MFMAs, M-halves)
//   Out(16x16)= Wv(16x32) . T(32x16)     (1 MFMA, T via LDS bounce)
// X window shifted -8 in both dims => aligned float4 loads, band w[k-idx-3],
// and edge zero-pad == zeroing one k-group fragment. 5 channels: p,t,pp,tt,pt.
// Wave-private LDS transpose buffers (no barriers). f16 fragments, f32 accum.

namespace {
constexpr int W = 320, H = 320, B = 128;
constexpr int NSTRIP = 20;            // y strips of 16 rows
constexpr int WPB = 4;                // waves per block
constexpr int NWAVE = B * NSTRIP * 2; // 5120 (x halves of 160 cols)
constexpr int NBLK = NWAVE / WPB;     // 1280
constexpr float C1 = 1.0e-4f;
constexpr float C2 = 9.0e-4f;
constexpr int NSLOT = 128;
constexpr int SSTR = 16;
constexpr int RSTR = 20;              // LDS row-pair stride (u32) -> 2-way banks
constexpr int LPCH = 16 * RSTR;       // u32 per channel buffer
}

typedef _Float16 h8 __attribute__((ext_vector_type(8)));
typedef float f4 __attribute__((ext_vector_type(4)));

union H8U { h8 h; uint u[4]; };

__device__ __forceinline__ uint pkrtz_u(float a, float b) {
  return __builtin_bit_cast(uint, __builtin_amdgcn_cvt_pkrtz(a, b));
}

__device__ __forceinline__ float rcpf(float x) {
  float r;
  asm("v_rcp_f32 %0, %1" : "=v"(r) : "v"(x));
  return r;
}

#define MFMA(A, Bv, Cv) __builtin_amdgcn_mfma_f32_16x16x32_f16((A), (Bv), (Cv), 0, 0, 0)

// Load next tile's 8 aligned float4s (2 per fragment).
#define LOADT(TT)                                                             \
  do {                                                                        \
    const int x0_ = xbase + 16 * (TT);                                        \
    const bool gz_ = (x0_ == 0 && g == 0) || (x0_ == 304 && g == 3);          \
    const int cb_ = gz_ ? 0 : (x0_ - 8 + 8 * g);                              \
    gzc = gz_;                                                                \
    p1a = *(const float4*)(Pp + rowoff1 + cb_);                               \
    p1b = *(const float4*)(Pp + rowoff1 + cb_ + 4);                           \
    p2a = *(const float4*)(Pp + rowoff2 + cb_);                               \
    p2b = *(const float4*)(Pp + rowoff2 + cb_ + 4);                           \
    t1a = *(const float4*)(Pt + rowoff1 + cb_);                               \
    t1b = *(const float4*)(Pt + rowoff1 + cb_ + 4);                           \
    t2a = *(const float4*)(Pt + rowoff2 + cb_);                               \
    t2b = *(const float4*)(Pt + rowoff2 + cb_ + 4);                           \
  } while (0)

#define BUILD(DST, RA, RB, MSK)                                               \
  do {                                                                        \
    DST.u[0] = (MSK) ? pkrtz_u(RA.x, RA.y) : 0u;                              \
    DST.u[1] = (MSK) ? pkrtz_u(RA.z, RA.w) : 0u;                              \
    DST.u[2] = (MSK) ? pkrtz_u(RB.x, RB.y) : 0u;                              \
    DST.u[3] = (MSK) ? pkrtz_u(RB.z, RB.w) : 0u;                              \
  } while (0)

// Step 1: two MFMAs (M-halves) -> pack f32 pairs -> LDS (rows as row-pairs).
#define STEP1(A1, A2, CH)                                                     \
  do {                                                                        \
    f4 c1_ = MFMA(A1, WB.h, z);                                               \
    f4 c2_ = MFMA(A2, WB.h, z);                                               \
    uint* buf_ = &ldsT[wid][CH][0];                                           \
    buf_[(2 * g + 0) * RSTR + n] = pkrtz_u(c1_[0], c1_[1]);                   \
    buf_[(2 * g + 1) * RSTR + n] = pkrtz_u(c1_[2], c1_[3]);                   \
    buf_[(8 + 2 * g) * RSTR + n] = pkrtz_u(c2_[0], c2_[1]);                   \
    buf_[(9 + 2 * g) * RSTR + n] = pkrtz_u(c2_[2], c2_[3]);                   \
  } while (0)

// Step 2: read B-fragment (k-run 8g..8g+7 = row-pairs 4g..4g+3) + final MFMA.
#define STEP2(CH, DD)                                                         \
  do {                                                                        \
    const uint* buf_ = &ldsT[wid][CH][0];                                     \
    H8U bf_;                                                                  \
    bf_.u[0] = buf_[(4 * g + 0) * RSTR + n];                                  \
    bf_.u[1] = buf_[(4 * g + 1) * RSTR + n];                                  \
    bf_.u[2] = buf_[(4 * g + 2) * RSTR + n];                                  \
    bf_.u[3] = buf_[(4 * g + 3) * RSTR + n];                                  \
    DD = MFMA(WB.h, bf_.h, z);                                                \
  } while (0)

__global__ __launch_bounds__(256) void ssim_mfma(
    const float* __restrict__ pred, const float* __restrict__ targ,
    float* __restrict__ sink, int slotmask, int sstr) {
  __shared__ uint ldsT[WPB][5][LPCH];

  const int l = threadIdx.x & 63;
  const int wid = threadIdx.x >> 6;
  const int n = l & 15;   // col (step1 B / step2 D col; A row)
  const int g = l >> 4;   // k-octet group

  const int s = blockIdx.x * WPB + wid;
  const int img = s / (NSTRIP * 2);
  const int rr = s % (NSTRIP * 2);
  const int half = rr & 1;
  const int y0 = (rr >> 1) * 16;
  const int xbase = half * 160;

  const float* __restrict__ Pp = pred + (size_t)img * (W * H);
  const float* __restrict__ Pt = targ + (size_t)img * (W * H);

  // ---- weight fragment: elem i -> w[(8g + i) - (l&15) - 3], band [0,10] ----
  H8U WB;
  {
    const float KK = -0.32059889f;    // -0.5/(1.5^2) * log2(e)
    const float INVS = 0.26601171f;   // 1/sum of 11 taps
#pragma unroll
    for (int j = 0; j < 4; ++j) {
      const int d0 = 8 * g + 2 * j - n - 3;
      const int d1 = d0 + 1;
      const float df0 = (float)(d0 - 5);
      const float df1 = (float)(d1 - 5);
      const float e0 = exp2f(df0 * df0 * KK) * INVS;
      const float e1 = exp2f(df1 * df1 * KK) * INVS;
      const float f0 = (d0 >= 0 && d0 <= 10) ? e0 : 0.f;
      const float f1 = (d1 >= 0 && d1 <= 10) ? e1 : 0.f;
      WB.u[j] = pkrtz_u(f0, f1);
    }
  }

  // Row geometry (constant over tiles): M1 rows y0-8+n, M2 rows y0+8+n.
  const int r1 = y0 - 8 + n;
  const int r2 = y0 + 8 + n;
  const bool v1 = (r1 >= 0);          // r1 <= 311 always
  const bool v2 = (r2 < H);           // r2 >= 8 always
  const size_t rowoff1 = (size_t)(v1 ? r1 : 0) * W;
  const size_t rowoff2 = (size_t)(v2 ? r2 : 0) * W;

  float acc = 0.f;
  const f4 z = {0.f, 0.f, 0.f, 0.f};

  float4 p1a, p1b, p2a, p2b, t1a, t1b, t2a, t2b;
  bool gzc;
  LOADT(0);

#pragma unroll 1
  for (int tt = 0; tt < 10; ++tt) {
    const bool m1 = v1 && !gzc;
    const bool m2 = v2 && !gzc;

    H8U fp1, fp2, ft1, ft2;
    BUILD(fp1, p1a, p1b, m1);
    BUILD(fp2, p2a, p2b, m2);
    BUILD(ft1, t1a, t1b, m1);
    BUILD(ft2, t2a, t2b, m2);

    if (tt < 9) LOADT(tt + 1);   // prefetch next tile under this tile's math

    // ---- step 1: horizontal blur of 5 channels -> LDS ----
    STEP1(fp1.h, fp2.h, 0);                       // p
    STEP1(ft1.h, ft2.h, 1);                       // t
    {
      H8U d1, d2;
      d1.h = fp1.h * fp1.h; d2.h = fp2.h * fp2.h;
      STEP1(d1.h, d2.h, 2);                       // pp
      d1.h = ft1.h * ft1.h; d2.h = ft2.h * ft2.h;
      STEP1(d1.h, d2.h, 3);                       // tt
      d1.h = fp1.h * ft1.h; d2.h = fp2.h * ft2.h;
      STEP1(d1.h, d2.h, 4);                       // pt
    }

    // ---- step 2: vertical blur (read transposed T) ----
    f4 D0, D1, D2, D3, D4;
    STEP2(0, D0);
    STEP2(1, D1);
    STEP2(2, D2);
    STEP2(3, D3);
    STEP2(4, D4);

    // ---- SSIM on 4 px/lane (D layout: col n, rows y0 + 4g + q) ----
#pragma unroll
    for (int q = 0; q < 4; ++q) {
      const float mx = D0[q], my = D1[q];
      const float xx = D2[q], yy = D3[q], xy = D4[q];
      const float mxx = mx * mx, myy = my * my, mxy = mx * my;
      const float vx = xx - mxx, vy = yy - myy, vxy = xy - mxy;
      const float num = fmaf(2.f, mxy, C1) * fmaf(2.f, vxy, C2);
      const float den = (mxx + myy + C1) * (vx + vy + C2);
      acc = fmaf(num, rcpf(den), acc);
    }
  }

  // ---- wave reduce + spread atomics ----
#pragma unroll
  for (int off = 32; off; off >>= 1) acc += __shfl_xor(acc, off, 64);
  if (l == 0) atomicAdd(sink + (s & slotmask) * sstr, acc);
}

__global__ void ssim_final(const float* __restrict__ sink, int nslot, int sstr,
                           float* __restrict__ out) {
  const int tid = threadIdx.x;  // 64 threads
  float v = 0.f;
  for (int q = tid; q < nslot; q += 64) v += sink[q * sstr];
#pragma unroll
  for (int off = 32; off; off >>= 1) v += __shfl_xor(v, off, 64);
  if (tid == 0) out[0] = 1.f - v / 13107200.f;
}

extern "C" void kernel_launch(void* const* d_in, const int* in_sizes, int n_in,
                              void* d_out, int out_size, void* d_ws, size_t ws_size,
                              hipStream_t stream) {
  (void)in_sizes; (void)n_in; (void)out_size;
  const float* pred = (const float*)d_in[0];
  const float* targ = (const float*)d_in[1];
  float* out = (float*)d_out;

  float* sink;
  int nslot, sstr;
  const size_t need = (size_t)NSLOT * SSTR * sizeof(float);
  if (ws_size >= need) {
    sink = (float*)d_ws;
    nslot = NSLOT;
    sstr = SSTR;
  } else {
    sink = out;
    nslot = 1;
    sstr = 0;
  }
  (void)hipMemsetAsync(sink, 0, nslot == 1 ? sizeof(float) : need, stream);
  ssim_mfma<<<dim3(NBLK), dim3(256), 0, stream>>>(pred, targ, sink, nslot - 1, sstr);
  ssim_final<<<1, 64, 0, stream>>>(sink, nslot, sstr, out);
}